// Round 10
// baseline (177.044 us; speedup 1.0000x reference)
//
#include <hip/hip_runtime.h>

#define NH 12

typedef __bf16 bf16x8 __attribute__((ext_vector_type(8)));
typedef __bf16 bf16x4 __attribute__((ext_vector_type(4)));
typedef float f32x4 __attribute__((ext_vector_type(4)));

typedef const __attribute__((address_space(1))) void* gas_ptr;
typedef __attribute__((address_space(3))) void* las_ptr;

__device__ __forceinline__ void gload_lds16(const __bf16* g, __bf16* l) {
    __builtin_amdgcn_global_load_lds((gas_ptr)g, (las_ptr)l, 16, 0, 0);
}

// Q scale folded with log2(e): attention runs in exp2 domain.
#define QSCALE 0.18033688011112042f   // 0.125 * log2(e)

// ---------------- fp32 -> bf16 conversion (weights only; hs is fused into gemm0) ----------------
__global__ void convert_w(const float* __restrict__ w1,
                          const float* __restrict__ w2,
                          __bf16* __restrict__ wq,
                          __bf16* __restrict__ wo) {
    const int C1 = 221184;   // 1769472/8
    const int C2 = 73728;    // 589824/8
    int i = blockIdx.x * blockDim.x + threadIdx.x;
    const int stride = gridDim.x * blockDim.x;
    for (; i < C1 + C2; i += stride) {
        const float* src; __bf16* dst; int j;
        if (i < C1) { src = w1; dst = wq; j = i; }
        else        { src = w2; dst = wo; j = i - C1; }
        f32x4 v0 = *(const f32x4*)(src + (size_t)j * 8);
        f32x4 v1 = *(const f32x4*)(src + (size_t)j * 8 + 4);
        bf16x8 o;
#pragma unroll
        for (int r = 0; r < 4; r++) { o[r] = (__bf16)v0[r]; o[4 + r] = (__bf16)v1[r]; }
        *(bf16x8*)(dst + (size_t)j * 8) = o;
    }
}

// ---------------- NT bf16 MFMA GEMM: C = A(MxK) * B(NxK)^T + bias ----------------
// BM x 128 tile, BK=64, NBUF=2 (1 __syncthreads per K-step), XOR-swizzled LDS,
// bijective XCD swizzle.
// MODE 0 (QKV proj): A is FP32 (raw hidden states) — reg-staged with fused
//   fp32->bf16 convert: global loads issue BEFORE compute, cvt+ds_write AFTER
//   (T14 async split). vT blocks use the LDS-staged coalescing epilogue.
// MODE 1 (out proj): A is bf16, gload_lds staged; fp32 direct epilogue.
template <int MODE, int BM>
__global__ __launch_bounds__(BM * 4) void gemm_nt(
    const void* __restrict__ Av, const __bf16* __restrict__ Bm,
    const float* __restrict__ bias,
    __bf16* __restrict__ qb, __bf16* __restrict__ kb, __bf16* __restrict__ vT,
    float* __restrict__ outf, int M, int N, int K, int NXB)
{
    constexpr int THREADS = BM * 4;
    constexpr int ASZ = BM * 64 * 2;          // bytes per A buffer
    constexpr int BSZ = 128 * 64 * 2;         // bytes per B buffer
    constexpr int BUNITS = 1024 / THREADS;    // B stage units per thread
    constexpr int SMEMSZ = (MODE == 0) ? 66560 : (2 * ASZ + 2 * BSZ);
    __shared__ __align__(16) char SMEM[SMEMSZ];

    const int t = threadIdx.x;
    const int lane = t & 63;
    const int w = t >> 6;
    const int wr = w >> 2, wc = w & 3;        // wave tile 64x32
    const int fr = lane & 15, g4 = lane >> 4;

    const int cpx = gridDim.x >> 3;
    const int orig = blockIdx.x;
    const int swz = (orig & 7) * cpx + (orig >> 3);
    const int bx = swz % NXB, by = swz / NXB;
    const int m0 = by * BM, n0 = bx * 128;

    f32x4 acc[4][2];
    const f32x4 z4 = {0.f, 0.f, 0.f, 0.f};
#pragma unroll
    for (int i = 0; i < 4; i++)
#pragma unroll
        for (int j = 0; j < 2; j++) acc[i][j] = z4;

    const int kSteps = K >> 6;

    auto As_ = [&](int b) { return (__bf16*)(SMEM + b * ASZ); };
    auto Bs_ = [&](int b) { return (__bf16*)(SMEM + 2 * ASZ + b * BSZ); };

    // A unit geometry (2 units of 8 elems per thread, both BM variants)
    int rowA[2], cbA[2], cA[2];
#pragma unroll
    for (int u = 0; u < 2; u++) {
        const int c = u * THREADS + t;
        rowA[u] = c >> 3;
        cbA[u] = ((c & 7) ^ ((c >> 3) & 7)) * 8;
        cA[u] = c;
    }

    const float*  Af = (const float*)Av;
    const __bf16* Ab = (const __bf16*)Av;

    f32x4 ar[2][2];
    auto aload = [&](int tk) {    // MODE 0: issue fp32 A loads (32B/unit)
#pragma unroll
        for (int u = 0; u < 2; u++) {
            const float* p = Af + (size_t)(m0 + rowA[u]) * K + tk * 64 + cbA[u];
            ar[u][0] = *(const f32x4*)p;
            ar[u][1] = *(const f32x4*)(p + 4);
        }
    };
    auto awrite = [&](int b) {    // MODE 0: cvt + ds_write (after compute)
#pragma unroll
        for (int u = 0; u < 2; u++) {
            bf16x8 o;
#pragma unroll
            for (int r = 0; r < 4; r++) { o[r] = (__bf16)ar[u][0][r]; o[4 + r] = (__bf16)ar[u][1][r]; }
            *(bf16x8*)(As_(b) + cA[u] * 8) = o;
        }
    };
    auto astage = [&](int tk, int b) {   // MODE 1: bf16 A via gload_lds
#pragma unroll
        for (int u = 0; u < 2; u++)
            gload_lds16(Ab + (size_t)(m0 + rowA[u]) * K + tk * 64 + cbA[u], As_(b) + cA[u] * 8);
    };
    auto bstage = [&](int tk, int b) {
#pragma unroll
        for (int u = 0; u < BUNITS; u++) {
            const int c = u * THREADS + t;
            const int row = c >> 3;
            const int cb = ((c & 7) ^ (row & 7)) * 8;
            gload_lds16(Bm + (size_t)(n0 + row) * K + tk * 64 + cb, Bs_(b) + c * 8);
        }
    };

    auto compute = [&](int cur) {
#pragma unroll
        for (int h = 0; h < 2; h++) {
            bf16x8 af[4], bfr[2];
#pragma unroll
            for (int i = 0; i < 4; i++) {
                const int r = wr * 64 + i * 16 + fr;
                af[i] = *(const bf16x8*)&As_(cur)[r * 64 + (((h * 4 + g4) ^ (r & 7)) * 8)];
            }
#pragma unroll
            for (int j = 0; j < 2; j++) {
                const int r = wc * 32 + j * 16 + fr;
                bfr[j] = *(const bf16x8*)&Bs_(cur)[r * 64 + (((h * 4 + g4) ^ (r & 7)) * 8)];
            }
            __builtin_amdgcn_s_setprio(1);
#pragma unroll
            for (int i = 0; i < 4; i++)
#pragma unroll
                for (int j = 0; j < 2; j++)
                    acc[i][j] = __builtin_amdgcn_mfma_f32_16x16x32_bf16(af[i], bfr[j], acc[i][j], 0, 0, 0);
            __builtin_amdgcn_s_setprio(0);
        }
    };

    if constexpr (MODE == 0) { aload(0); awrite(0); } else { astage(0, 0); }
    bstage(0, 0);
    __syncthreads();
    int cur = 0;
    for (int ks = 0; ks < kSteps; ks++) {
        if (ks < kSteps - 1) {
            if constexpr (MODE == 0) aload(ks + 1);      // issue early (hide under MFMA)
            else                     astage(ks + 1, cur ^ 1);
            bstage(ks + 1, cur ^ 1);
        }
        compute(cur);
        if constexpr (MODE == 0) { if (ks < kSteps - 1) awrite(cur ^ 1); }  // write late
        __syncthreads();
        cur ^= 1;
    }

    if constexpr (MODE == 1) {
#pragma unroll
        for (int j = 0; j < 2; j++) {
            const int gc = n0 + wc * 32 + j * 16 + fr;
            const float bv = bias[gc];
#pragma unroll
            for (int i = 0; i < 4; i++)
#pragma unroll
                for (int r = 0; r < 4; r++) {
                    const int gr = m0 + wr * 64 + i * 16 + g4 * 4 + r;
                    outf[(size_t)gr * N + gc] = acc[i][j][r] + bv;
                }
        }
    } else {
        const int which = (n0 >= 1536) ? 2 : (n0 >= 768 ? 1 : 0);
        if (which < 2) {
#pragma unroll
            for (int j = 0; j < 2; j++) {
                const int gc = n0 + wc * 32 + j * 16 + fr;
                const float bv = bias[gc];
                const int jj = gc - which * 768;
                const int head = jj >> 6, dim = jj & 63;
#pragma unroll
                for (int i = 0; i < 4; i++)
#pragma unroll
                    for (int r = 0; r < 4; r++) {
                        const int gr = m0 + wr * 64 + i * 16 + g4 * 4 + r;
                        const int s = gr >> 3, b = gr & 7;
                        const size_t n = (size_t)(b * NH + head);
                        const float val = acc[i][j][r] + bv;
                        if (which == 0) qb[(n * 1024 + s) * 64 + dim] = (__bf16)(val * QSCALE);
                        else            kb[(n * 1024 + s) * 64 + dim] = (__bf16)val;
                    }
            }
        } else {
            // vT: LDS-staged coalescing epilogue (padded [128][130] f32)
            float* Cw = (float*)SMEM;
#pragma unroll
            for (int j = 0; j < 2; j++) {
                const int col = wc * 32 + j * 16 + fr;
                const float bv = bias[n0 + col];
#pragma unroll
                for (int i = 0; i < 4; i++)
#pragma unroll
                    for (int r = 0; r < 4; r++) {
                        const int l = wr * 64 + i * 16 + g4 * 4 + r;
                        Cw[l * 130 + col] = acc[i][j][r] + bv;
                    }
            }
            __syncthreads();
            const int hbase = (n0 - 1536) >> 6;
            const int s0 = m0 >> 3;
#pragma unroll
            for (int u = 0; u < 2; u++) {
                const int c = u * THREADS + t;
                const int b = c >> 7;
                const int hd = (c >> 6) & 1;
                const int dim = c & 63;
                const size_t n = (size_t)(b * NH + hbase + hd);
                __bf16* dst = vT + (n * 64 + dim) * 1024 + s0;
                bf16x8 o0, o1;
#pragma unroll
                for (int sl = 0; sl < 8; sl++)
                    o0[sl] = (__bf16)Cw[(sl * 8 + b) * 130 + hd * 64 + dim];
#pragma unroll
                for (int sl = 0; sl < 8; sl++)
                    o1[sl] = (__bf16)Cw[((sl + 8) * 8 + b) * 130 + hd * 64 + dim];
                *(bf16x8*)dst = o0;
                *(bf16x8*)(dst + 8) = o1;
            }
        }
    }
}

// ---------------- flash attention ----------------
// K staged in LDS (XOR-swizzled, double-buffered); V read DIRECT from global
// (L2-resident per XCD — m169 pattern: staging L2-fit data is pure overhead).
// vf loads issue at chunk top, ~500 cyc ahead of PV.
__global__ __launch_bounds__(512) void attn_kernel(
    const __bf16* __restrict__ qb, const __bf16* __restrict__ kb,
    const __bf16* __restrict__ vT, __bf16* __restrict__ ctx)
{
    __shared__ __bf16 Kl[2][64 * 64];
    __shared__ __bf16 Pl[8][16 * 64];
    const int t = threadIdx.x, lane = t & 63, w = t >> 6;

    const int orig = blockIdx.x;
    const int swz = (orig & 7) * 96 + (orig >> 3);
    const int n = swz >> 3;
    const int q0 = (swz & 7) * 128;
    const int fr = lane & 15, g4 = lane >> 4;
    const int fx = fr & 7;

    const __bf16* qptr = qb + ((size_t)n * 1024 + q0 + w * 16 + fr) * 64 + g4 * 8;
    const bf16x8 qf0 = *(const bf16x8*)qptr;
    const bf16x8 qf1 = *(const bf16x8*)(qptr + 32);

    float mval = -1e30f, lval = 0.f;
    const f32x4 z4 = {0.f, 0.f, 0.f, 0.f};
    f32x4 o[4] = {z4, z4, z4, z4};

    const int srow = t >> 3;
    const int scb  = (t & 7) ^ (srow & 7);
    const __bf16* kbase = kb + (size_t)n * 65536;
    const __bf16* vbase = vT + (size_t)n * 65536;

    gload_lds16(kbase + (size_t)srow * 64 + scb * 8, &Kl[0][t * 8]);
    __syncthreads();

    int cur = 0;
    for (int kc = 0; kc < 16; kc++) {
        if (kc < 15)
            gload_lds16(kbase + (size_t)((kc + 1) * 64 + srow) * 64 + scb * 8, &Kl[cur ^ 1][t * 8]);

        // ---- V fragments direct from global (issue early; used in PV) ----
        bf16x8 vf[2][4];
#pragma unroll
        for (int ks = 0; ks < 2; ks++)
#pragma unroll
            for (int dt = 0; dt < 4; dt++)
                vf[ks][dt] = *(const bf16x8*)(vbase + (size_t)(dt * 16 + fr) * 1024 + kc * 64 + ks * 32 + g4 * 8);

        // ---- QK^T (swapped): sc[tt][r] = score[key = 16tt+4g4+r][q = fr] ----
        f32x4 sc[4];
        __builtin_amdgcn_s_setprio(1);
#pragma unroll
        for (int tt = 0; tt < 4; tt++) {
            const int row = (tt * 16 + fr) * 64;
            bf16x8 kf0 = *(const bf16x8*)&Kl[cur][row + ((g4 ^ fx) * 8)];
            bf16x8 kf1 = *(const bf16x8*)&Kl[cur][row + (((4 + g4) ^ fx) * 8)];
            f32x4 s = __builtin_amdgcn_mfma_f32_16x16x32_bf16(kf0, qf0, z4, 0, 0, 0);
            s = __builtin_amdgcn_mfma_f32_16x16x32_bf16(kf1, qf1, s, 0, 0, 0);
            sc[tt] = s;
        }
        __builtin_amdgcn_s_setprio(0);

        // ---- in-lane softmax over 16 values + cross-g4 (2 shfl) ----
        float a[16];
#pragma unroll
        for (int tt = 0; tt < 4; tt++)
#pragma unroll
            for (int r = 0; r < 4; r++) a[tt * 4 + r] = sc[tt][r];

        float m8[8];
#pragma unroll
        for (int i = 0; i < 8; i++) m8[i] = fmaxf(a[i], a[i + 8]);
        float m4a = fmaxf(m8[0], m8[4]), m4b = fmaxf(m8[1], m8[5]);
        float m4c = fmaxf(m8[2], m8[6]), m4d = fmaxf(m8[3], m8[7]);
        float pmax = fmaxf(fmaxf(m4a, m4b), fmaxf(m4c, m4d));
        pmax = fmaxf(pmax, __shfl_xor(pmax, 16));
        pmax = fmaxf(pmax, __shfl_xor(pmax, 32));

        if (pmax > mval + 8.0f) {
            const float sf = __builtin_amdgcn_exp2f(mval - pmax);
            lval *= sf;
#pragma unroll
            for (int dt = 0; dt < 4; dt++) o[dt] *= sf;
            mval = pmax;
        }

        float p[16];
#pragma unroll
        for (int i = 0; i < 16; i++) p[i] = __builtin_amdgcn_exp2f(a[i] - mval);
        float s8[8];
#pragma unroll
        for (int i = 0; i < 8; i++) s8[i] = p[i] + p[i + 8];
        float s4a = s8[0] + s8[4], s4b = s8[1] + s8[5];
        float s4c = s8[2] + s8[6], s4d = s8[3] + s8[7];
        float psum = (s4a + s4b) + (s4c + s4d);
        psum += __shfl_xor(psum, 16);
        psum += __shfl_xor(psum, 32);
        lval += psum;

#pragma unroll
        for (int tt = 0; tt < 4; tt++) {
            bf16x4 pk;
            pk[0] = (__bf16)p[tt * 4 + 0];
            pk[1] = (__bf16)p[tt * 4 + 1];
            pk[2] = (__bf16)p[tt * 4 + 2];
            pk[3] = (__bf16)p[tt * 4 + 3];
            const int blk = (2 * tt + (g4 >> 1)) ^ fx;
            *(bf16x4*)&Pl[w][fr * 64 + blk * 8 + (g4 & 1) * 4] = pk;
        }

        // ---- PV (swapped): o[dt][r] -> d = 16dt+4g4+r, q = fr ----
        __builtin_amdgcn_s_setprio(1);
#pragma unroll
        for (int ks = 0; ks < 2; ks++) {
            bf16x8 pa = *(const bf16x8*)&Pl[w][fr * 64 + (((4 * ks + g4) ^ fx) * 8)];
#pragma unroll
            for (int dt = 0; dt < 4; dt++)
                o[dt] = __builtin_amdgcn_mfma_f32_16x16x32_bf16(vf[ks][dt], pa, o[dt], 0, 0, 0);
        }
        __builtin_amdgcn_s_setprio(0);

        if (kc < 15) __syncthreads();
        cur ^= 1;
    }

    const int b = n / NH, head = n % NH;
    const float rl = 1.0f / lval;
    const int srw = q0 + w * 16 + fr;
    __bf16* cbase = ctx + ((size_t)srw * 8 + b) * 768 + head * 64;
#pragma unroll
    for (int dt = 0; dt < 4; dt++) {
        bf16x4 ov;
#pragma unroll
        for (int r = 0; r < 4; r++) ov[r] = (__bf16)(o[dt][r] * rl);
        *(bf16x4*)&cbase[dt * 16 + g4 * 4] = ov;
    }
}

extern "C" void kernel_launch(void* const* d_in, const int* in_sizes, int n_in,
                              void* d_out, int out_size, void* d_ws, size_t ws_size,
                              hipStream_t stream) {
    const float* hs = (const float*)d_in[0];
    const float* w1 = (const float*)d_in[1];
    const float* b1 = (const float*)d_in[2];
    const float* w2 = (const float*)d_in[3];
    const float* b2 = (const float*)d_in[4];
    float* out = (float*)d_out;

    char* ws = (char*)d_ws;
    __bf16* qb  = (__bf16*)(ws);
    __bf16* kb  = (__bf16*)(ws + 12582912);
    __bf16* vT  = (__bf16*)(ws + 25165824);
    __bf16* Ctx = (__bf16*)(ws + 37748736);
    __bf16* Wq  = (__bf16*)(ws + 50331648);
    __bf16* Wo  = (__bf16*)(ws + 53870592);

    convert_w<<<512, 256, 0, stream>>>(w1, w2, Wq, Wo);
    gemm_nt<0, 128><<<1152, 512, 0, stream>>>(hs, Wq, b1, qb, kb, vT, nullptr, 8192, 2304, 768, 18);
    attn_kernel<<<768, 512, 0, stream>>>(qb, kb, vT, Ctx);
    gemm_nt<1, 64><<<768, 256, 0, stream>>>(Ctx, Wo, b2, nullptr, nullptr, nullptr, out, 8192, 768, 768, 6);
}

// Round 11
// 117.165 us; speedup vs baseline: 1.5111x; 1.5111x over previous
//
#include <hip/hip_runtime.h>

#define NH 12

typedef __bf16 bf16x8 __attribute__((ext_vector_type(8)));
typedef __bf16 bf16x4 __attribute__((ext_vector_type(4)));
typedef float f32x4 __attribute__((ext_vector_type(4)));

typedef const __attribute__((address_space(1))) void* gas_ptr;
typedef __attribute__((address_space(3))) void* las_ptr;

__device__ __forceinline__ void gload_lds16(const __bf16* g, __bf16* l) {
    __builtin_amdgcn_global_load_lds((gas_ptr)g, (las_ptr)l, 16, 0, 0);
}

// Q scale folded with log2(e): attention runs in exp2 domain.
#define QSCALE 0.18033688011112042f   // 0.125 * log2(e)

// ---------------- fp32 -> bf16 conversion (weights only; hs fused into gemm0) ----------------
__global__ void convert_w(const float* __restrict__ w1,
                          const float* __restrict__ w2,
                          __bf16* __restrict__ wq,
                          __bf16* __restrict__ wo) {
    const int C1 = 221184;   // 1769472/8
    const int C2 = 73728;    // 589824/8
    int i = blockIdx.x * blockDim.x + threadIdx.x;
    const int stride = gridDim.x * blockDim.x;
    for (; i < C1 + C2; i += stride) {
        const float* src; __bf16* dst; int j;
        if (i < C1) { src = w1; dst = wq; j = i; }
        else        { src = w2; dst = wo; j = i - C1; }
        f32x4 v0 = *(const f32x4*)(src + (size_t)j * 8);
        f32x4 v1 = *(const f32x4*)(src + (size_t)j * 8 + 4);
        bf16x8 o;
#pragma unroll
        for (int r = 0; r < 4; r++) { o[r] = (__bf16)v0[r]; o[4 + r] = (__bf16)v1[r]; }
        *(bf16x8*)(dst + (size_t)j * 8) = o;
    }
}

// ---------------- NT bf16 MFMA GEMM: C = A(MxK) * B(NxK)^T + bias ----------------
// BM x 128 tile, BK=64, NBUF=2 (1 __syncthreads per K-step), XOR-swizzled LDS,
// bijective XCD swizzle.
// MODE 0 (QKV proj): A is FP32 (raw hidden states) — reg-staged with fused
//   fp32->bf16 convert (loads issue before compute, cvt+ds_write after).
//   vT blocks use the LDS-staged coalescing epilogue.
// MODE 1 (out proj): A is bf16, gload_lds staged; fp32 direct epilogue.
template <int MODE, int BM>
__global__ __launch_bounds__(BM * 4) void gemm_nt(
    const void* __restrict__ Av, const __bf16* __restrict__ Bm,
    const float* __restrict__ bias,
    __bf16* __restrict__ qb, __bf16* __restrict__ kb, __bf16* __restrict__ vT,
    float* __restrict__ outf, int M, int N, int K, int NXB)
{
    constexpr int THREADS = BM * 4;
    constexpr int ASZ = BM * 64 * 2;          // bytes per A buffer
    constexpr int BSZ = 128 * 64 * 2;         // bytes per B buffer
    constexpr int BUNITS = 1024 / THREADS;    // B stage units per thread
    constexpr int SMEMSZ = (MODE == 0) ? 66560 : (2 * ASZ + 2 * BSZ);
    __shared__ __align__(16) char SMEM[SMEMSZ];

    const int t = threadIdx.x;
    const int lane = t & 63;
    const int w = t >> 6;
    const int wr = w >> 2, wc = w & 3;        // wave tile 64x32
    const int fr = lane & 15, g4 = lane >> 4;

    const int cpx = gridDim.x >> 3;
    const int orig = blockIdx.x;
    const int swz = (orig & 7) * cpx + (orig >> 3);
    const int bx = swz % NXB, by = swz / NXB;
    const int m0 = by * BM, n0 = bx * 128;

    f32x4 acc[4][2];
    const f32x4 z4 = {0.f, 0.f, 0.f, 0.f};
#pragma unroll
    for (int i = 0; i < 4; i++)
#pragma unroll
        for (int j = 0; j < 2; j++) acc[i][j] = z4;

    const int kSteps = K >> 6;

    auto As_ = [&](int b) { return (__bf16*)(SMEM + b * ASZ); };
    auto Bs_ = [&](int b) { return (__bf16*)(SMEM + 2 * ASZ + b * BSZ); };

    int rowA[2], cbA[2], cA[2];
#pragma unroll
    for (int u = 0; u < 2; u++) {
        const int c = u * THREADS + t;
        rowA[u] = c >> 3;
        cbA[u] = ((c & 7) ^ ((c >> 3) & 7)) * 8;
        cA[u] = c;
    }

    const float*  Af = (const float*)Av;
    const __bf16* Ab = (const __bf16*)Av;

    f32x4 ar[2][2];
    auto aload = [&](int tk) {
#pragma unroll
        for (int u = 0; u < 2; u++) {
            const float* p = Af + (size_t)(m0 + rowA[u]) * K + tk * 64 + cbA[u];
            ar[u][0] = *(const f32x4*)p;
            ar[u][1] = *(const f32x4*)(p + 4);
        }
    };
    auto awrite = [&](int b) {
#pragma unroll
        for (int u = 0; u < 2; u++) {
            bf16x8 o;
#pragma unroll
            for (int r = 0; r < 4; r++) { o[r] = (__bf16)ar[u][0][r]; o[4 + r] = (__bf16)ar[u][1][r]; }
            *(bf16x8*)(As_(b) + cA[u] * 8) = o;
        }
    };
    auto astage = [&](int tk, int b) {
#pragma unroll
        for (int u = 0; u < 2; u++)
            gload_lds16(Ab + (size_t)(m0 + rowA[u]) * K + tk * 64 + cbA[u], As_(b) + cA[u] * 8);
    };
    auto bstage = [&](int tk, int b) {
#pragma unroll
        for (int u = 0; u < BUNITS; u++) {
            const int c = u * THREADS + t;
            const int row = c >> 3;
            const int cb = ((c & 7) ^ (row & 7)) * 8;
            gload_lds16(Bm + (size_t)(n0 + row) * K + tk * 64 + cb, Bs_(b) + c * 8);
        }
    };

    auto compute = [&](int cur) {
#pragma unroll
        for (int h = 0; h < 2; h++) {
            bf16x8 af[4], bfr[2];
#pragma unroll
            for (int i = 0; i < 4; i++) {
                const int r = wr * 64 + i * 16 + fr;
                af[i] = *(const bf16x8*)&As_(cur)[r * 64 + (((h * 4 + g4) ^ (r & 7)) * 8)];
            }
#pragma unroll
            for (int j = 0; j < 2; j++) {
                const int r = wc * 32 + j * 16 + fr;
                bfr[j] = *(const bf16x8*)&Bs_(cur)[r * 64 + (((h * 4 + g4) ^ (r & 7)) * 8)];
            }
            __builtin_amdgcn_s_setprio(1);
#pragma unroll
            for (int i = 0; i < 4; i++)
#pragma unroll
                for (int j = 0; j < 2; j++)
                    acc[i][j] = __builtin_amdgcn_mfma_f32_16x16x32_bf16(af[i], bfr[j], acc[i][j], 0, 0, 0);
            __builtin_amdgcn_s_setprio(0);
        }
    };

    if constexpr (MODE == 0) { aload(0); awrite(0); } else { astage(0, 0); }
    bstage(0, 0);
    __syncthreads();
    int cur = 0;
    for (int ks = 0; ks < kSteps; ks++) {
        if (ks < kSteps - 1) {
            if constexpr (MODE == 0) aload(ks + 1);      // issue early (hide under MFMA)
            else                     astage(ks + 1, cur ^ 1);
            bstage(ks + 1, cur ^ 1);
        }
        compute(cur);
        if constexpr (MODE == 0) { if (ks < kSteps - 1) awrite(cur ^ 1); }  // write late
        __syncthreads();
        cur ^= 1;
    }

    if constexpr (MODE == 1) {
#pragma unroll
        for (int j = 0; j < 2; j++) {
            const int gc = n0 + wc * 32 + j * 16 + fr;
            const float bv = bias[gc];
#pragma unroll
            for (int i = 0; i < 4; i++)
#pragma unroll
                for (int r = 0; r < 4; r++) {
                    const int gr = m0 + wr * 64 + i * 16 + g4 * 4 + r;
                    outf[(size_t)gr * N + gc] = acc[i][j][r] + bv;
                }
        }
    } else {
        const int which = (n0 >= 1536) ? 2 : (n0 >= 768 ? 1 : 0);
        if (which < 2) {
#pragma unroll
            for (int j = 0; j < 2; j++) {
                const int gc = n0 + wc * 32 + j * 16 + fr;
                const float bv = bias[gc];
                const int jj = gc - which * 768;
                const int head = jj >> 6, dim = jj & 63;
#pragma unroll
                for (int i = 0; i < 4; i++)
#pragma unroll
                    for (int r = 0; r < 4; r++) {
                        const int gr = m0 + wr * 64 + i * 16 + g4 * 4 + r;
                        const int s = gr >> 3, b = gr & 7;
                        const size_t n = (size_t)(b * NH + head);
                        const float val = acc[i][j][r] + bv;
                        if (which == 0) qb[(n * 1024 + s) * 64 + dim] = (__bf16)(val * QSCALE);
                        else            kb[(n * 1024 + s) * 64 + dim] = (__bf16)val;
                    }
            }
        } else {
            // vT: LDS-staged coalescing epilogue (padded [128][130] f32)
            float* Cw = (float*)SMEM;
#pragma unroll
            for (int j = 0; j < 2; j++) {
                const int col = wc * 32 + j * 16 + fr;
                const float bv = bias[n0 + col];
#pragma unroll
                for (int i = 0; i < 4; i++)
#pragma unroll
                    for (int r = 0; r < 4; r++) {
                        const int l = wr * 64 + i * 16 + g4 * 4 + r;
                        Cw[l * 130 + col] = acc[i][j][r] + bv;
                    }
            }
            __syncthreads();
            const int hbase = (n0 - 1536) >> 6;
            const int s0 = m0 >> 3;
#pragma unroll
            for (int u = 0; u < 2; u++) {
                const int c = u * THREADS + t;
                const int b = c >> 7;
                const int hd = (c >> 6) & 1;
                const int dim = c & 63;
                const size_t n = (size_t)(b * NH + hbase + hd);
                __bf16* dst = vT + (n * 64 + dim) * 1024 + s0;
                bf16x8 o0, o1;
#pragma unroll
                for (int sl = 0; sl < 8; sl++)
                    o0[sl] = (__bf16)Cw[(sl * 8 + b) * 130 + hd * 64 + dim];
#pragma unroll
                for (int sl = 0; sl < 8; sl++)
                    o1[sl] = (__bf16)Cw[((sl + 8) * 8 + b) * 130 + hd * 64 + dim];
                *(bf16x8*)dst = o0;
                *(bf16x8*)(dst + 8) = o1;
            }
        }
    }
}

// ---------------- flash attention (known-good R8 version: staged K AND V) ----------------
__global__ __launch_bounds__(512) void attn_kernel(
    const __bf16* __restrict__ qb, const __bf16* __restrict__ kb,
    const __bf16* __restrict__ vT, __bf16* __restrict__ ctx)
{
    __shared__ __bf16 Kl[2][64 * 64];
    __shared__ __bf16 Vl[2][64 * 64];
    __shared__ __bf16 Pl[8][16 * 64];
    const int t = threadIdx.x, lane = t & 63, w = t >> 6;

    const int orig = blockIdx.x;
    const int swz = (orig & 7) * 96 + (orig >> 3);
    const int n = swz >> 3;
    const int q0 = (swz & 7) * 128;
    const int fr = lane & 15, g4 = lane >> 4;
    const int fx = fr & 7;

    const __bf16* qptr = qb + ((size_t)n * 1024 + q0 + w * 16 + fr) * 64 + g4 * 8;
    const bf16x8 qf0 = *(const bf16x8*)qptr;
    const bf16x8 qf1 = *(const bf16x8*)(qptr + 32);

    float mval = -1e30f, lval = 0.f;
    const f32x4 z4 = {0.f, 0.f, 0.f, 0.f};
    f32x4 o[4] = {z4, z4, z4, z4};

    const int srow = t >> 3;
    const int scb  = (t & 7) ^ (srow & 7);
    const __bf16* kbase = kb + (size_t)n * 65536;
    const __bf16* vbase = vT + (size_t)n * 65536;

    gload_lds16(kbase + (size_t)srow * 64 + scb * 8,   &Kl[0][t * 8]);
    gload_lds16(vbase + (size_t)srow * 1024 + scb * 8, &Vl[0][t * 8]);
    __syncthreads();

    int cur = 0;
    for (int kc = 0; kc < 16; kc++) {
        if (kc < 15) {
            const int t0 = (kc + 1) * 64;
            gload_lds16(kbase + (size_t)(t0 + srow) * 64 + scb * 8,  &Kl[cur ^ 1][t * 8]);
            gload_lds16(vbase + (size_t)srow * 1024 + t0 + scb * 8,  &Vl[cur ^ 1][t * 8]);
        }

        // ---- QK^T (swapped): sc[tt][r] = score[key = 16tt+4g4+r][q = fr] ----
        f32x4 sc[4];
        __builtin_amdgcn_s_setprio(1);
#pragma unroll
        for (int tt = 0; tt < 4; tt++) {
            const int row = (tt * 16 + fr) * 64;
            bf16x8 kf0 = *(const bf16x8*)&Kl[cur][row + ((g4 ^ fx) * 8)];
            bf16x8 kf1 = *(const bf16x8*)&Kl[cur][row + (((4 + g4) ^ fx) * 8)];
            f32x4 s = __builtin_amdgcn_mfma_f32_16x16x32_bf16(kf0, qf0, z4, 0, 0, 0);
            s = __builtin_amdgcn_mfma_f32_16x16x32_bf16(kf1, qf1, s, 0, 0, 0);
            sc[tt] = s;
        }
        __builtin_amdgcn_s_setprio(0);

        // ---- in-lane softmax over 16 values + cross-g4 (2 shfl) ----
        float a[16];
#pragma unroll
        for (int tt = 0; tt < 4; tt++)
#pragma unroll
            for (int r = 0; r < 4; r++) a[tt * 4 + r] = sc[tt][r];

        float m8[8];
#pragma unroll
        for (int i = 0; i < 8; i++) m8[i] = fmaxf(a[i], a[i + 8]);
        float m4a = fmaxf(m8[0], m8[4]), m4b = fmaxf(m8[1], m8[5]);
        float m4c = fmaxf(m8[2], m8[6]), m4d = fmaxf(m8[3], m8[7]);
        float pmax = fmaxf(fmaxf(m4a, m4b), fmaxf(m4c, m4d));
        pmax = fmaxf(pmax, __shfl_xor(pmax, 16));
        pmax = fmaxf(pmax, __shfl_xor(pmax, 32));

        if (pmax > mval + 8.0f) {
            const float sf = __builtin_amdgcn_exp2f(mval - pmax);
            lval *= sf;
#pragma unroll
            for (int dt = 0; dt < 4; dt++) o[dt] *= sf;
            mval = pmax;
        }

        float p[16];
#pragma unroll
        for (int i = 0; i < 16; i++) p[i] = __builtin_amdgcn_exp2f(a[i] - mval);
        float s8[8];
#pragma unroll
        for (int i = 0; i < 8; i++) s8[i] = p[i] + p[i + 8];
        float s4a = s8[0] + s8[4], s4b = s8[1] + s8[5];
        float s4c = s8[2] + s8[6], s4d = s8[3] + s8[7];
        float psum = (s4a + s4b) + (s4c + s4d);
        psum += __shfl_xor(psum, 16);
        psum += __shfl_xor(psum, 32);
        lval += psum;

#pragma unroll
        for (int tt = 0; tt < 4; tt++) {
            bf16x4 pk;
            pk[0] = (__bf16)p[tt * 4 + 0];
            pk[1] = (__bf16)p[tt * 4 + 1];
            pk[2] = (__bf16)p[tt * 4 + 2];
            pk[3] = (__bf16)p[tt * 4 + 3];
            const int blk = (2 * tt + (g4 >> 1)) ^ fx;
            *(bf16x4*)&Pl[w][fr * 64 + blk * 8 + (g4 & 1) * 4] = pk;
        }

        // ---- PV (swapped): o[dt][r] -> d = 16dt+4g4+r, q = fr ----
        __builtin_amdgcn_s_setprio(1);
#pragma unroll
        for (int ks = 0; ks < 2; ks++) {
            bf16x8 pa = *(const bf16x8*)&Pl[w][fr * 64 + (((4 * ks + g4) ^ fx) * 8)];
#pragma unroll
            for (int dt = 0; dt < 4; dt++) {
                bf16x8 vf = *(const bf16x8*)&Vl[cur][(dt * 16 + fr) * 64 + (((4 * ks + g4) ^ fx) * 8)];
                o[dt] = __builtin_amdgcn_mfma_f32_16x16x32_bf16(vf, pa, o[dt], 0, 0, 0);
            }
        }
        __builtin_amdgcn_s_setprio(0);

        if (kc < 15) __syncthreads();
        cur ^= 1;
    }

    const int b = n / NH, head = n % NH;
    const float rl = 1.0f / lval;
    const int srw = q0 + w * 16 + fr;
    __bf16* cbase = ctx + ((size_t)srw * 8 + b) * 768 + head * 64;
#pragma unroll
    for (int dt = 0; dt < 4; dt++) {
        bf16x4 ov;
#pragma unroll
        for (int r = 0; r < 4; r++) ov[r] = (__bf16)(o[dt][r] * rl);
        *(bf16x4*)&cbase[dt * 16 + g4 * 4] = ov;
    }
}

extern "C" void kernel_launch(void* const* d_in, const int* in_sizes, int n_in,
                              void* d_out, int out_size, void* d_ws, size_t ws_size,
                              hipStream_t stream) {
    const float* hs = (const float*)d_in[0];
    const float* w1 = (const float*)d_in[1];
    const float* b1 = (const float*)d_in[2];
    const float* w2 = (const float*)d_in[3];
    const float* b2 = (const float*)d_in[4];
    float* out = (float*)d_out;

    char* ws = (char*)d_ws;
    __bf16* qb  = (__bf16*)(ws);
    __bf16* kb  = (__bf16*)(ws + 12582912);
    __bf16* vT  = (__bf16*)(ws + 25165824);
    __bf16* Ctx = (__bf16*)(ws + 37748736);
    __bf16* Wq  = (__bf16*)(ws + 50331648);
    __bf16* Wo  = (__bf16*)(ws + 53870592);

    convert_w<<<512, 256, 0, stream>>>(w1, w2, Wq, Wo);
    gemm_nt<0, 128><<<1152, 512, 0, stream>>>(hs, Wq, b1, qb, kb, vT, nullptr, 8192, 2304, 768, 18);
    attn_kernel<<<768, 512, 0, stream>>>(qb, kb, vT, Ctx);
    gemm_nt<1, 64><<<768, 256, 0, stream>>>(Ctx, Wo, b2, nullptr, nullptr, nullptr, out, 8192, 768, 768, 6);
}

// Round 12
// 111.407 us; speedup vs baseline: 1.5892x; 1.0517x over previous
//
#include <hip/hip_runtime.h>

#define NH 12

typedef __bf16 bf16x8 __attribute__((ext_vector_type(8)));
typedef __bf16 bf16x4 __attribute__((ext_vector_type(4)));
typedef float f32x4 __attribute__((ext_vector_type(4)));

typedef const __attribute__((address_space(1))) void* gas_ptr;
typedef __attribute__((address_space(3))) void* las_ptr;

__device__ __forceinline__ void gload_lds16(const __bf16* g, __bf16* l) {
    __builtin_amdgcn_global_load_lds((gas_ptr)g, (las_ptr)l, 16, 0, 0);
}

// Q scale folded with log2(e): attention runs in exp2 domain.
#define QSCALE 0.18033688011112042f   // 0.125 * log2(e)

// ---------------- fp32 -> bf16 conversion (vectorized: 8 elems/thread/iter) ----------------
__global__ void convert_kernel(const float* __restrict__ hs,
                               const float* __restrict__ w1,
                               const float* __restrict__ w2,
                               __bf16* __restrict__ xh,
                               __bf16* __restrict__ wq,
                               __bf16* __restrict__ wo) {
    const long long C0 = 786432;   // 6291456/8
    const long long C1 = 221184;   // 1769472/8
    const long long C2 = 73728;    // 589824/8
    long long i = (long long)blockIdx.x * blockDim.x + threadIdx.x;
    const long long stride = (long long)gridDim.x * blockDim.x;
    for (; i < C0 + C1 + C2; i += stride) {
        const float* src; __bf16* dst; long long j;
        if (i < C0)           { src = hs; dst = xh; j = i; }
        else if (i < C0 + C1) { src = w1; dst = wq; j = i - C0; }
        else                  { src = w2; dst = wo; j = i - C0 - C1; }
        f32x4 v0 = *(const f32x4*)(src + j * 8);
        f32x4 v1 = *(const f32x4*)(src + j * 8 + 4);
        bf16x8 o;
#pragma unroll
        for (int r = 0; r < 4; r++) { o[r] = (__bf16)v0[r]; o[4 + r] = (__bf16)v1[r]; }
        *(bf16x8*)(dst + j * 8) = o;
    }
}

// ---------------- NT bf16 MFMA GEMM: C = A(MxK) * B(NxK)^T + bias ----------------
// BM x 128 tile, BK=64, NBUF=2 (1 __syncthreads per K-step), XOR-swizzled LDS.
// MODE 0: two-phase bx ordering per XCD (A-slice + B-half = 3.25MB < 4MB L2);
//         vT blocks use the LDS-staged coalescing epilogue.
// MODE 1: plain bijective XCD swizzle; fp32 direct epilogue.
template <int MODE, int BM>
__global__ __launch_bounds__(BM * 4) void gemm_nt(
    const __bf16* __restrict__ A, const __bf16* __restrict__ Bm,
    const float* __restrict__ bias,
    __bf16* __restrict__ qb, __bf16* __restrict__ kb, __bf16* __restrict__ vT,
    float* __restrict__ outf, int M, int N, int K, int NXB)
{
    constexpr int THREADS = BM * 4;
    constexpr int ASZ = BM * 64 * 2;          // bytes per A buffer
    constexpr int BSZ = 128 * 64 * 2;         // bytes per B buffer
    constexpr int BUNITS = 1024 / THREADS;    // B stage units per thread
    constexpr int SMEMSZ = (MODE == 0) ? 66560 : (2 * ASZ + 2 * BSZ);
    __shared__ __align__(16) char SMEM[SMEMSZ];

    const int t = threadIdx.x;
    const int lane = t & 63;
    const int w = t >> 6;
    const int wr = w >> 2, wc = w & 3;        // wave tile 64x32
    const int fr = lane & 15, g4 = lane >> 4;

    const int cpx = gridDim.x >> 3;
    const int orig = blockIdx.x;
    int bx, by;
    if constexpr (MODE == 0) {
        // two-phase bx ordering within each XCD: keeps (A-slice + B-half)
        // L2-resident. by = xcd*rowsPer + rem/halfN, bx = half*halfN + rem%halfN.
        const int xcd = orig & 7, idx = orig >> 3;
        const int halfSz = cpx >> 1;
        const int half = idx / halfSz, rem = idx - half * halfSz;
        const int halfN = NXB >> 1;
        by = xcd * (cpx / NXB) + rem / halfN;
        bx = half * halfN + rem % halfN;
    } else {
        const int swz = (orig & 7) * cpx + (orig >> 3);
        bx = swz % NXB; by = swz / NXB;
    }
    const int m0 = by * BM, n0 = bx * 128;

    f32x4 acc[4][2];
    const f32x4 z4 = {0.f, 0.f, 0.f, 0.f};
#pragma unroll
    for (int i = 0; i < 4; i++)
#pragma unroll
        for (int j = 0; j < 2; j++) acc[i][j] = z4;

    const int kSteps = K >> 6;

    auto As_ = [&](int b) { return (__bf16*)(SMEM + b * ASZ); };
    auto Bs_ = [&](int b) { return (__bf16*)(SMEM + 2 * ASZ + b * BSZ); };

    auto stage = [&](int tk, int b) {
#pragma unroll
        for (int u = 0; u < 2; u++) {
            const int c = u * THREADS + t;
            const int row = c >> 3;
            const int cb = ((c & 7) ^ (row & 7)) * 8;   // pre-swizzled source
            gload_lds16(A + (size_t)(m0 + row) * K + tk * 64 + cb, As_(b) + c * 8);
        }
#pragma unroll
        for (int u = 0; u < BUNITS; u++) {
            const int c = u * THREADS + t;
            const int row = c >> 3;
            const int cb = ((c & 7) ^ (row & 7)) * 8;
            gload_lds16(Bm + (size_t)(n0 + row) * K + tk * 64 + cb, Bs_(b) + c * 8);
        }
    };

    auto compute = [&](int cur) {
#pragma unroll
        for (int h = 0; h < 2; h++) {
            bf16x8 af[4], bfr[2];
#pragma unroll
            for (int i = 0; i < 4; i++) {
                const int r = wr * 64 + i * 16 + fr;
                af[i] = *(const bf16x8*)&As_(cur)[r * 64 + (((h * 4 + g4) ^ (r & 7)) * 8)];
            }
#pragma unroll
            for (int j = 0; j < 2; j++) {
                const int r = wc * 32 + j * 16 + fr;
                bfr[j] = *(const bf16x8*)&Bs_(cur)[r * 64 + (((h * 4 + g4) ^ (r & 7)) * 8)];
            }
            __builtin_amdgcn_s_setprio(1);
#pragma unroll
            for (int i = 0; i < 4; i++)
#pragma unroll
                for (int j = 0; j < 2; j++)
                    acc[i][j] = __builtin_amdgcn_mfma_f32_16x16x32_bf16(af[i], bfr[j], acc[i][j], 0, 0, 0);
            __builtin_amdgcn_s_setprio(0);
        }
    };

    stage(0, 0);
    __syncthreads();
    int cur = 0;
    for (int ks = 0; ks < kSteps; ks++) {
        if (ks < kSteps - 1) stage(ks + 1, cur ^ 1);
        compute(cur);
        __syncthreads();
        cur ^= 1;
    }

    if constexpr (MODE == 1) {
#pragma unroll
        for (int j = 0; j < 2; j++) {
            const int gc = n0 + wc * 32 + j * 16 + fr;
            const float bv = bias[gc];
#pragma unroll
            for (int i = 0; i < 4; i++)
#pragma unroll
                for (int r = 0; r < 4; r++) {
                    const int gr = m0 + wr * 64 + i * 16 + g4 * 4 + r;
                    outf[(size_t)gr * N + gc] = acc[i][j][r] + bv;
                }
        }
    } else {
        const int which = (n0 >= 1536) ? 2 : (n0 >= 768 ? 1 : 0);
        if (which < 2) {
#pragma unroll
            for (int j = 0; j < 2; j++) {
                const int gc = n0 + wc * 32 + j * 16 + fr;
                const float bv = bias[gc];
                const int jj = gc - which * 768;
                const int head = jj >> 6, dim = jj & 63;
#pragma unroll
                for (int i = 0; i < 4; i++)
#pragma unroll
                    for (int r = 0; r < 4; r++) {
                        const int gr = m0 + wr * 64 + i * 16 + g4 * 4 + r;
                        const int s = gr >> 3, b = gr & 7;
                        const size_t n = (size_t)(b * NH + head);
                        const float val = acc[i][j][r] + bv;
                        if (which == 0) qb[(n * 1024 + s) * 64 + dim] = (__bf16)(val * QSCALE);
                        else            kb[(n * 1024 + s) * 64 + dim] = (__bf16)val;
                    }
            }
        } else {
            // vT: LDS-staged coalescing epilogue (padded [128][130] f32)
            float* Cw = (float*)SMEM;
#pragma unroll
            for (int j = 0; j < 2; j++) {
                const int col = wc * 32 + j * 16 + fr;
                const float bv = bias[n0 + col];
#pragma unroll
                for (int i = 0; i < 4; i++)
#pragma unroll
                    for (int r = 0; r < 4; r++) {
                        const int l = wr * 64 + i * 16 + g4 * 4 + r;
                        Cw[l * 130 + col] = acc[i][j][r] + bv;
                    }
            }
            __syncthreads();
            const int hbase = (n0 - 1536) >> 6;
            const int s0 = m0 >> 3;
#pragma unroll
            for (int u = 0; u < 2; u++) {
                const int c = u * THREADS + t;
                const int b = c >> 7;
                const int hd = (c >> 6) & 1;
                const int dim = c & 63;
                const size_t n = (size_t)(b * NH + hbase + hd);
                __bf16* dst = vT + (n * 64 + dim) * 1024 + s0;
                bf16x8 o0, o1;
#pragma unroll
                for (int sl = 0; sl < 8; sl++)
                    o0[sl] = (__bf16)Cw[(sl * 8 + b) * 130 + hd * 64 + dim];
#pragma unroll
                for (int sl = 0; sl < 8; sl++)
                    o1[sl] = (__bf16)Cw[((sl + 8) * 8 + b) * 130 + hd * 64 + dim];
                *(bf16x8*)dst = o0;
                *(bf16x8*)(dst + 8) = o1;
            }
        }
    }
}

// ---------------- flash attention (staged K AND V; Pl-write hoisted) ----------------
__global__ __launch_bounds__(512) void attn_kernel(
    const __bf16* __restrict__ qb, const __bf16* __restrict__ kb,
    const __bf16* __restrict__ vT, __bf16* __restrict__ ctx)
{
    __shared__ __bf16 Kl[2][64 * 64];
    __shared__ __bf16 Vl[2][64 * 64];
    __shared__ __bf16 Pl[8][16 * 64];
    const int t = threadIdx.x, lane = t & 63, w = t >> 6;

    const int orig = blockIdx.x;
    const int swz = (orig & 7) * 96 + (orig >> 3);
    const int n = swz >> 3;
    const int q0 = (swz & 7) * 128;
    const int fr = lane & 15, g4 = lane >> 4;
    const int fx = fr & 7;

    const __bf16* qptr = qb + ((size_t)n * 1024 + q0 + w * 16 + fr) * 64 + g4 * 8;
    const bf16x8 qf0 = *(const bf16x8*)qptr;
    const bf16x8 qf1 = *(const bf16x8*)(qptr + 32);

    float mval = -1e30f, lval = 0.f;
    const f32x4 z4 = {0.f, 0.f, 0.f, 0.f};
    f32x4 o[4] = {z4, z4, z4, z4};

    const int srow = t >> 3;
    const int scb  = (t & 7) ^ (srow & 7);
    const __bf16* kbase = kb + (size_t)n * 65536;
    const __bf16* vbase = vT + (size_t)n * 65536;

    gload_lds16(kbase + (size_t)srow * 64 + scb * 8,   &Kl[0][t * 8]);
    gload_lds16(vbase + (size_t)srow * 1024 + scb * 8, &Vl[0][t * 8]);
    __syncthreads();

    int cur = 0;
    for (int kc = 0; kc < 16; kc++) {
        if (kc < 15) {
            const int t0 = (kc + 1) * 64;
            gload_lds16(kbase + (size_t)(t0 + srow) * 64 + scb * 8,  &Kl[cur ^ 1][t * 8]);
            gload_lds16(vbase + (size_t)srow * 1024 + t0 + scb * 8,  &Vl[cur ^ 1][t * 8]);
        }

        // ---- QK^T (swapped): sc[tt][r] = score[key = 16tt+4g4+r][q = fr] ----
        f32x4 sc[4];
        __builtin_amdgcn_s_setprio(1);
#pragma unroll
        for (int tt = 0; tt < 4; tt++) {
            const int row = (tt * 16 + fr) * 64;
            bf16x8 kf0 = *(const bf16x8*)&Kl[cur][row + ((g4 ^ fx) * 8)];
            bf16x8 kf1 = *(const bf16x8*)&Kl[cur][row + (((4 + g4) ^ fx) * 8)];
            f32x4 s = __builtin_amdgcn_mfma_f32_16x16x32_bf16(kf0, qf0, z4, 0, 0, 0);
            s = __builtin_amdgcn_mfma_f32_16x16x32_bf16(kf1, qf1, s, 0, 0, 0);
            sc[tt] = s;
        }
        __builtin_amdgcn_s_setprio(0);

        // ---- in-lane softmax over 16 values + cross-g4 (2 shfl) ----
        float a[16];
#pragma unroll
        for (int tt = 0; tt < 4; tt++)
#pragma unroll
            for (int r = 0; r < 4; r++) a[tt * 4 + r] = sc[tt][r];

        float m8[8];
#pragma unroll
        for (int i = 0; i < 8; i++) m8[i] = fmaxf(a[i], a[i + 8]);
        float m4a = fmaxf(m8[0], m8[4]), m4b = fmaxf(m8[1], m8[5]);
        float m4c = fmaxf(m8[2], m8[6]), m4d = fmaxf(m8[3], m8[7]);
        float pmax = fmaxf(fmaxf(m4a, m4b), fmaxf(m4c, m4d));
        pmax = fmaxf(pmax, __shfl_xor(pmax, 16));
        pmax = fmaxf(pmax, __shfl_xor(pmax, 32));

        if (pmax > mval + 8.0f) {
            const float sf = __builtin_amdgcn_exp2f(mval - pmax);
            lval *= sf;
#pragma unroll
            for (int dt = 0; dt < 4; dt++) o[dt] *= sf;
            mval = pmax;
        }

        float p[16];
#pragma unroll
        for (int i = 0; i < 16; i++) p[i] = __builtin_amdgcn_exp2f(a[i] - mval);

        // ---- pack & write Pl FIRST (ds_writes drain under the sum tree) ----
#pragma unroll
        for (int tt = 0; tt < 4; tt++) {
            bf16x4 pk;
            pk[0] = (__bf16)p[tt * 4 + 0];
            pk[1] = (__bf16)p[tt * 4 + 1];
            pk[2] = (__bf16)p[tt * 4 + 2];
            pk[3] = (__bf16)p[tt * 4 + 3];
            const int blk = (2 * tt + (g4 >> 1)) ^ fx;
            *(bf16x4*)&Pl[w][fr * 64 + blk * 8 + (g4 & 1) * 4] = pk;
        }

        float s8[8];
#pragma unroll
        for (int i = 0; i < 8; i++) s8[i] = p[i] + p[i + 8];
        float s4a = s8[0] + s8[4], s4b = s8[1] + s8[5];
        float s4c = s8[2] + s8[6], s4d = s8[3] + s8[7];
        float psum = (s4a + s4b) + (s4c + s4d);
        psum += __shfl_xor(psum, 16);
        psum += __shfl_xor(psum, 32);
        lval += psum;

        // ---- PV (swapped): o[dt][r] -> d = 16dt+4g4+r, q = fr ----
        __builtin_amdgcn_s_setprio(1);
#pragma unroll
        for (int ks = 0; ks < 2; ks++) {
            bf16x8 pa = *(const bf16x8*)&Pl[w][fr * 64 + (((4 * ks + g4) ^ fx) * 8)];
#pragma unroll
            for (int dt = 0; dt < 4; dt++) {
                bf16x8 vf = *(const bf16x8*)&Vl[cur][(dt * 16 + fr) * 64 + (((4 * ks + g4) ^ fx) * 8)];
                o[dt] = __builtin_amdgcn_mfma_f32_16x16x32_bf16(vf, pa, o[dt], 0, 0, 0);
            }
        }
        __builtin_amdgcn_s_setprio(0);

        if (kc < 15) __syncthreads();
        cur ^= 1;
    }

    const int b = n / NH, head = n % NH;
    const float rl = 1.0f / lval;
    const int srw = q0 + w * 16 + fr;
    __bf16* cbase = ctx + ((size_t)srw * 8 + b) * 768 + head * 64;
#pragma unroll
    for (int dt = 0; dt < 4; dt++) {
        bf16x4 ov;
#pragma unroll
        for (int r = 0; r < 4; r++) ov[r] = (__bf16)(o[dt][r] * rl);
        *(bf16x4*)&cbase[dt * 16 + g4 * 4] = ov;
    }
}

extern "C" void kernel_launch(void* const* d_in, const int* in_sizes, int n_in,
                              void* d_out, int out_size, void* d_ws, size_t ws_size,
                              hipStream_t stream) {
    const float* hs = (const float*)d_in[0];
    const float* w1 = (const float*)d_in[1];
    const float* b1 = (const float*)d_in[2];
    const float* w2 = (const float*)d_in[3];
    const float* b2 = (const float*)d_in[4];
    float* out = (float*)d_out;

    char* ws = (char*)d_ws;
    __bf16* qb  = (__bf16*)(ws);
    __bf16* kb  = (__bf16*)(ws + 12582912);
    __bf16* vT  = (__bf16*)(ws + 25165824);
    __bf16* Xh  = (__bf16*)(ws + 37748736);
    __bf16* Wq  = (__bf16*)(ws + 50331648);
    __bf16* Wo  = (__bf16*)(ws + 53870592);
    __bf16* Ctx = Xh;                            // Xh dead after gemm0 -> reuse

    convert_kernel<<<2048, 256, 0, stream>>>(hs, w1, w2, Xh, Wq, Wo);
    gemm_nt<0, 128><<<1152, 512, 0, stream>>>(Xh, Wq, b1, qb, kb, vT, nullptr, 8192, 2304, 768, 18);
    attn_kernel<<<768, 512, 0, stream>>>(qb, kb, vT, Ctx);
    gemm_nt<1, 64><<<768, 256, 0, stream>>>(Ctx, Wo, b2, nullptr, nullptr, nullptr, out, 8192, 768, 768, 6);
}

// Round 13
// 108.520 us; speedup vs baseline: 1.6314x; 1.0266x over previous
//
#include <hip/hip_runtime.h>

#define NH 12

typedef __bf16 bf16x8 __attribute__((ext_vector_type(8)));
typedef __bf16 bf16x4 __attribute__((ext_vector_type(4)));
typedef float f32x4 __attribute__((ext_vector_type(4)));

typedef const __attribute__((address_space(1))) void* gas_ptr;
typedef __attribute__((address_space(3))) void* las_ptr;

__device__ __forceinline__ void gload_lds16(const __bf16* g, __bf16* l) {
    __builtin_amdgcn_global_load_lds((gas_ptr)g, (las_ptr)l, 16, 0, 0);
}

// Q scale folded with log2(e): attention runs in exp2 domain.
#define QSCALE 0.18033688011112042f   // 0.125 * log2(e)

// ---------------- fp32 -> bf16 conversion (vectorized: 8 elems/thread/iter) ----------------
__global__ void convert_kernel(const float* __restrict__ hs,
                               const float* __restrict__ w1,
                               const float* __restrict__ w2,
                               __bf16* __restrict__ xh,
                               __bf16* __restrict__ wq,
                               __bf16* __restrict__ wo) {
    const long long C0 = 786432;   // 6291456/8
    const long long C1 = 221184;   // 1769472/8
    const long long C2 = 73728;    // 589824/8
    long long i = (long long)blockIdx.x * blockDim.x + threadIdx.x;
    const long long stride = (long long)gridDim.x * blockDim.x;
    for (; i < C0 + C1 + C2; i += stride) {
        const float* src; __bf16* dst; long long j;
        if (i < C0)           { src = hs; dst = xh; j = i; }
        else if (i < C0 + C1) { src = w1; dst = wq; j = i - C0; }
        else                  { src = w2; dst = wo; j = i - C0 - C1; }
        f32x4 v0 = *(const f32x4*)(src + j * 8);
        f32x4 v1 = *(const f32x4*)(src + j * 8 + 4);
        bf16x8 o;
#pragma unroll
        for (int r = 0; r < 4; r++) { o[r] = (__bf16)v0[r]; o[4 + r] = (__bf16)v1[r]; }
        *(bf16x8*)(dst + j * 8) = o;
    }
}

// ---------------- NT bf16 MFMA GEMM: C = A(MxK) * B(NxK)^T + bias ----------------
// BM x 128 tile, BK=64, NBUF=2 (1 __syncthreads per K-step), XOR-swizzled LDS.
// MODE 0: two-phase bx ordering per XCD (A-slice + B-half = 3.25MB < 4MB L2);
//         vT blocks use the LDS-staged coalescing epilogue.
// MODE 1: plain bijective XCD swizzle; fp32 direct epilogue.
template <int MODE, int BM>
__global__ __launch_bounds__(BM * 4) void gemm_nt(
    const __bf16* __restrict__ A, const __bf16* __restrict__ Bm,
    const float* __restrict__ bias,
    __bf16* __restrict__ qb, __bf16* __restrict__ kb, __bf16* __restrict__ vT,
    float* __restrict__ outf, int M, int N, int K, int NXB)
{
    constexpr int THREADS = BM * 4;
    constexpr int ASZ = BM * 64 * 2;          // bytes per A buffer
    constexpr int BSZ = 128 * 64 * 2;         // bytes per B buffer
    constexpr int BUNITS = 1024 / THREADS;    // B stage units per thread
    constexpr int SMEMSZ = (MODE == 0) ? 66560 : (2 * ASZ + 2 * BSZ);
    __shared__ __align__(16) char SMEM[SMEMSZ];

    const int t = threadIdx.x;
    const int lane = t & 63;
    const int w = t >> 6;
    const int wr = w >> 2, wc = w & 3;        // wave tile 64x32
    const int fr = lane & 15, g4 = lane >> 4;

    const int cpx = gridDim.x >> 3;
    const int orig = blockIdx.x;
    int bx, by;
    if constexpr (MODE == 0) {
        const int xcd = orig & 7, idx = orig >> 3;
        const int halfSz = cpx >> 1;
        const int half = idx / halfSz, rem = idx - half * halfSz;
        const int halfN = NXB >> 1;
        by = xcd * (cpx / NXB) + rem / halfN;
        bx = half * halfN + rem % halfN;
    } else {
        const int swz = (orig & 7) * cpx + (orig >> 3);
        bx = swz % NXB; by = swz / NXB;
    }
    const int m0 = by * BM, n0 = bx * 128;

    f32x4 acc[4][2];
    const f32x4 z4 = {0.f, 0.f, 0.f, 0.f};
#pragma unroll
    for (int i = 0; i < 4; i++)
#pragma unroll
        for (int j = 0; j < 2; j++) acc[i][j] = z4;

    const int kSteps = K >> 6;

    auto As_ = [&](int b) { return (__bf16*)(SMEM + b * ASZ); };
    auto Bs_ = [&](int b) { return (__bf16*)(SMEM + 2 * ASZ + b * BSZ); };

    auto stage = [&](int tk, int b) {
#pragma unroll
        for (int u = 0; u < 2; u++) {
            const int c = u * THREADS + t;
            const int row = c >> 3;
            const int cb = ((c & 7) ^ (row & 7)) * 8;
            gload_lds16(A + (size_t)(m0 + row) * K + tk * 64 + cb, As_(b) + c * 8);
        }
#pragma unroll
        for (int u = 0; u < BUNITS; u++) {
            const int c = u * THREADS + t;
            const int row = c >> 3;
            const int cb = ((c & 7) ^ (row & 7)) * 8;
            gload_lds16(Bm + (size_t)(n0 + row) * K + tk * 64 + cb, Bs_(b) + c * 8);
        }
    };

    auto compute = [&](int cur) {
#pragma unroll
        for (int h = 0; h < 2; h++) {
            bf16x8 af[4], bfr[2];
#pragma unroll
            for (int i = 0; i < 4; i++) {
                const int r = wr * 64 + i * 16 + fr;
                af[i] = *(const bf16x8*)&As_(cur)[r * 64 + (((h * 4 + g4) ^ (r & 7)) * 8)];
            }
#pragma unroll
            for (int j = 0; j < 2; j++) {
                const int r = wc * 32 + j * 16 + fr;
                bfr[j] = *(const bf16x8*)&Bs_(cur)[r * 64 + (((h * 4 + g4) ^ (r & 7)) * 8)];
            }
            __builtin_amdgcn_s_setprio(1);
#pragma unroll
            for (int i = 0; i < 4; i++)
#pragma unroll
                for (int j = 0; j < 2; j++)
                    acc[i][j] = __builtin_amdgcn_mfma_f32_16x16x32_bf16(af[i], bfr[j], acc[i][j], 0, 0, 0);
            __builtin_amdgcn_s_setprio(0);
        }
    };

    stage(0, 0);
    __syncthreads();
    int cur = 0;
    for (int ks = 0; ks < kSteps; ks++) {
        if (ks < kSteps - 1) stage(ks + 1, cur ^ 1);
        compute(cur);
        __syncthreads();
        cur ^= 1;
    }

    if constexpr (MODE == 1) {
#pragma unroll
        for (int j = 0; j < 2; j++) {
            const int gc = n0 + wc * 32 + j * 16 + fr;
            const float bv = bias[gc];
#pragma unroll
            for (int i = 0; i < 4; i++)
#pragma unroll
                for (int r = 0; r < 4; r++) {
                    const int gr = m0 + wr * 64 + i * 16 + g4 * 4 + r;
                    outf[(size_t)gr * N + gc] = acc[i][j][r] + bv;
                }
        }
    } else {
        const int which = (n0 >= 1536) ? 2 : (n0 >= 768 ? 1 : 0);
        if (which < 2) {
#pragma unroll
            for (int j = 0; j < 2; j++) {
                const int gc = n0 + wc * 32 + j * 16 + fr;
                const float bv = bias[gc];
                const int jj = gc - which * 768;
                const int head = jj >> 6, dim = jj & 63;
#pragma unroll
                for (int i = 0; i < 4; i++)
#pragma unroll
                    for (int r = 0; r < 4; r++) {
                        const int gr = m0 + wr * 64 + i * 16 + g4 * 4 + r;
                        const int s = gr >> 3, b = gr & 7;
                        const size_t n = (size_t)(b * NH + head);
                        const float val = acc[i][j][r] + bv;
                        if (which == 0) qb[(n * 1024 + s) * 64 + dim] = (__bf16)(val * QSCALE);
                        else            kb[(n * 1024 + s) * 64 + dim] = (__bf16)val;
                    }
            }
        } else {
            float* Cw = (float*)SMEM;
#pragma unroll
            for (int j = 0; j < 2; j++) {
                const int col = wc * 32 + j * 16 + fr;
                const float bv = bias[n0 + col];
#pragma unroll
                for (int i = 0; i < 4; i++)
#pragma unroll
                    for (int r = 0; r < 4; r++) {
                        const int l = wr * 64 + i * 16 + g4 * 4 + r;
                        Cw[l * 130 + col] = acc[i][j][r] + bv;
                    }
            }
            __syncthreads();
            const int hbase = (n0 - 1536) >> 6;
            const int s0 = m0 >> 3;
#pragma unroll
            for (int u = 0; u < 2; u++) {
                const int c = u * THREADS + t;
                const int b = c >> 7;
                const int hd = (c >> 6) & 1;
                const int dim = c & 63;
                const size_t n = (size_t)(b * NH + hbase + hd);
                __bf16* dst = vT + (n * 64 + dim) * 1024 + s0;
                bf16x8 o0, o1;
#pragma unroll
                for (int sl = 0; sl < 8; sl++)
                    o0[sl] = (__bf16)Cw[(sl * 8 + b) * 130 + hd * 64 + dim];
#pragma unroll
                for (int sl = 0; sl < 8; sl++)
                    o1[sl] = (__bf16)Cw[((sl + 8) * 8 + b) * 130 + hd * 64 + dim];
                *(bf16x8*)dst = o0;
                *(bf16x8*)(dst + 8) = o1;
            }
        }
    }
}

// ---------------- flash attention ----------------
// Ones-column trick: Vl has 80 rows; row 64 = ones (set once), so one extra
// PV MFMA per ks accumulates the softmax denominator in o[4] — the per-chunk
// sum tree + 2 shfl + lval update are GONE (rescale covers o[4] for free).
// Denominator sums the same bf16 P as the numerator (consistent rounding).
__global__ __launch_bounds__(512) void attn_kernel(
    const __bf16* __restrict__ qb, const __bf16* __restrict__ kb,
    const __bf16* __restrict__ vT, __bf16* __restrict__ ctx)
{
    __shared__ __bf16 Kl[2][64 * 64];
    __shared__ __bf16 Vl[2][80 * 64];   // rows 64..79: ones-row + zeros
    __shared__ __bf16 Pl[8][16 * 64];
    const int t = threadIdx.x, lane = t & 63, w = t >> 6;

    const int orig = blockIdx.x;
    const int swz = (orig & 7) * 96 + (orig >> 3);
    const int n = swz >> 3;
    const int q0 = (swz & 7) * 128;
    const int fr = lane & 15, g4 = lane >> 4;
    const int fx = fr & 7;

    const __bf16* qptr = qb + ((size_t)n * 1024 + q0 + w * 16 + fr) * 64 + g4 * 8;
    const bf16x8 qf0 = *(const bf16x8*)qptr;
    const bf16x8 qf1 = *(const bf16x8*)(qptr + 32);

    float mval = -1e30f;
    const f32x4 z4 = {0.f, 0.f, 0.f, 0.f};
    f32x4 o[5] = {z4, z4, z4, z4, z4};   // o[4] = denominator accumulator

    const int srow = t >> 3;
    const int scb  = (t & 7) ^ (srow & 7);
    const __bf16* kbase = kb + (size_t)n * 65536;
    const __bf16* vbase = vT + (size_t)n * 65536;

    // init ones/zero rows 64..79 of both V buffers (4 bf16 per thread)
    {
        const int b = t >> 8;
        const int rem = (t * 4) & 1023;
        const int row = 64 + (rem >> 6), col = rem & 63;
        bf16x4 v;
        const __bf16 f = (__bf16)((row == 64) ? 1.0f : 0.0f);
        v[0] = f; v[1] = f; v[2] = f; v[3] = f;
        *(bf16x4*)&Vl[b][row * 64 + col] = v;
    }

    gload_lds16(kbase + (size_t)srow * 64 + scb * 8,   &Kl[0][t * 8]);
    gload_lds16(vbase + (size_t)srow * 1024 + scb * 8, &Vl[0][t * 8]);
    __syncthreads();

    int cur = 0;
    for (int kc = 0; kc < 16; kc++) {
        if (kc < 15) {
            const int t0 = (kc + 1) * 64;
            gload_lds16(kbase + (size_t)(t0 + srow) * 64 + scb * 8,  &Kl[cur ^ 1][t * 8]);
            gload_lds16(vbase + (size_t)srow * 1024 + t0 + scb * 8,  &Vl[cur ^ 1][t * 8]);
        }

        // ---- QK^T (swapped): sc[tt][r] = score[key = 16tt+4g4+r][q = fr] ----
        f32x4 sc[4];
        __builtin_amdgcn_s_setprio(1);
#pragma unroll
        for (int tt = 0; tt < 4; tt++) {
            const int row = (tt * 16 + fr) * 64;
            bf16x8 kf0 = *(const bf16x8*)&Kl[cur][row + ((g4 ^ fx) * 8)];
            bf16x8 kf1 = *(const bf16x8*)&Kl[cur][row + (((4 + g4) ^ fx) * 8)];
            f32x4 s = __builtin_amdgcn_mfma_f32_16x16x32_bf16(kf0, qf0, z4, 0, 0, 0);
            s = __builtin_amdgcn_mfma_f32_16x16x32_bf16(kf1, qf1, s, 0, 0, 0);
            sc[tt] = s;
        }
        __builtin_amdgcn_s_setprio(0);

        float a[16];
#pragma unroll
        for (int tt = 0; tt < 4; tt++)
#pragma unroll
            for (int r = 0; r < 4; r++) a[tt * 4 + r] = sc[tt][r];

        // ---- max via max3-fusable triples ----
        const float t0m = fmaxf(fmaxf(a[0],  a[1]),  a[2]);
        const float t1m = fmaxf(fmaxf(a[3],  a[4]),  a[5]);
        const float t2m = fmaxf(fmaxf(a[6],  a[7]),  a[8]);
        const float t3m = fmaxf(fmaxf(a[9],  a[10]), a[11]);
        const float t4m = fmaxf(fmaxf(a[12], a[13]), a[14]);
        float pmax = fmaxf(fmaxf(fmaxf(t0m, t1m), t2m),
                           fmaxf(fmaxf(t3m, t4m), a[15]));
        pmax = fmaxf(pmax, __shfl_xor(pmax, 16));
        pmax = fmaxf(pmax, __shfl_xor(pmax, 32));

        if (pmax > mval + 8.0f) {      // defer-max (exp2 domain; o[4] rescales too)
            const float sf = __builtin_amdgcn_exp2f(mval - pmax);
#pragma unroll
            for (int dt = 0; dt < 5; dt++) o[dt] *= sf;
            mval = pmax;
        }

        float p[16];
#pragma unroll
        for (int i = 0; i < 16; i++) p[i] = __builtin_amdgcn_exp2f(a[i] - mval);

        // ---- pack & write Pl (ds_writes drain before PV reads) ----
#pragma unroll
        for (int tt = 0; tt < 4; tt++) {
            bf16x4 pk;
            pk[0] = (__bf16)p[tt * 4 + 0];
            pk[1] = (__bf16)p[tt * 4 + 1];
            pk[2] = (__bf16)p[tt * 4 + 2];
            pk[3] = (__bf16)p[tt * 4 + 3];
            const int blk = (2 * tt + (g4 >> 1)) ^ fx;
            *(bf16x4*)&Pl[w][fr * 64 + blk * 8 + (g4 & 1) * 4] = pk;
        }

        // ---- PV (swapped): o[dt][r] -> d = 16dt+4g4+r, q = fr; dt=4 = denom ----
        __builtin_amdgcn_s_setprio(1);
#pragma unroll
        for (int ks = 0; ks < 2; ks++) {
            bf16x8 pa = *(const bf16x8*)&Pl[w][fr * 64 + (((4 * ks + g4) ^ fx) * 8)];
#pragma unroll
            for (int dt = 0; dt < 5; dt++) {
                bf16x8 vf = *(const bf16x8*)&Vl[cur][(dt * 16 + fr) * 64 + (((4 * ks + g4) ^ fx) * 8)];
                o[dt] = __builtin_amdgcn_mfma_f32_16x16x32_bf16(vf, pa, o[dt], 0, 0, 0);
            }
        }
        __builtin_amdgcn_s_setprio(0);

        if (kc < 15) __syncthreads();
        cur ^= 1;
    }

    // denominator: lane g4==0 holds it in o[4][0] (d=64); broadcast via xor-add
    float lsum = o[4][0];
    lsum += __shfl_xor(lsum, 16);
    lsum += __shfl_xor(lsum, 32);

    const int b = n / NH, head = n % NH;
    const float rl = 1.0f / lsum;
    const int srw = q0 + w * 16 + fr;
    __bf16* cbase = ctx + ((size_t)srw * 8 + b) * 768 + head * 64;
#pragma unroll
    for (int dt = 0; dt < 4; dt++) {
        bf16x4 ov;
#pragma unroll
        for (int r = 0; r < 4; r++) ov[r] = (__bf16)(o[dt][r] * rl);
        *(bf16x4*)&cbase[dt * 16 + g4 * 4] = ov;
    }
}

extern "C" void kernel_launch(void* const* d_in, const int* in_sizes, int n_in,
                              void* d_out, int out_size, void* d_ws, size_t ws_size,
                              hipStream_t stream) {
    const float* hs = (const float*)d_in[0];
    const float* w1 = (const float*)d_in[1];
    const float* b1 = (const float*)d_in[2];
    const float* w2 = (const float*)d_in[3];
    const float* b2 = (const float*)d_in[4];
    float* out = (float*)d_out;

    char* ws = (char*)d_ws;
    __bf16* qb  = (__bf16*)(ws);
    __bf16* kb  = (__bf16*)(ws + 12582912);
    __bf16* vT  = (__bf16*)(ws + 25165824);
    __bf16* Xh  = (__bf16*)(ws + 37748736);
    __bf16* Wq  = (__bf16*)(ws + 50331648);
    __bf16* Wo  = (__bf16*)(ws + 53870592);
    __bf16* Ctx = Xh;                            // Xh dead after gemm0 -> reuse

    convert_kernel<<<2048, 256, 0, stream>>>(hs, w1, w2, Xh, Wq, Wo);
    gemm_nt<0, 128><<<1152, 512, 0, stream>>>(Xh, Wq, b1, qb, kb, vT, nullptr, 8192, 2304, 768, 18);
    attn_kernel<<<768, 512, 0, stream>>>(qb, kb, vT, Ctx);
    gemm_nt<1, 64><<<768, 256, 0, stream>>>(Ctx, Wo, b2, nullptr, nullptr, nullptr, out, 8192, 768, 768, 6);
}

// Round 14
// 105.467 us; speedup vs baseline: 1.6787x; 1.0289x over previous
//
#include <hip/hip_runtime.h>

#define NH 12

typedef __bf16 bf16x8 __attribute__((ext_vector_type(8)));
typedef __bf16 bf16x4 __attribute__((ext_vector_type(4)));
typedef float f32x4 __attribute__((ext_vector_type(4)));

typedef const __attribute__((address_space(1))) void* gas_ptr;
typedef __attribute__((address_space(3))) void* las_ptr;

__device__ __forceinline__ void gload_lds16(const __bf16* g, __bf16* l) {
    __builtin_amdgcn_global_load_lds((gas_ptr)g, (las_ptr)l, 16, 0, 0);
}

// Q scale folded with log2(e): attention runs in exp2 domain.
#define QSCALE 0.18033688011112042f   // 0.125 * log2(e)

// ---------------- fp32 -> bf16 conversion (vectorized: 8 elems/thread/iter) ----------------
__global__ void convert_kernel(const float* __restrict__ hs,
                               const float* __restrict__ w1,
                               const float* __restrict__ w2,
                               __bf16* __restrict__ xh,
                               __bf16* __restrict__ wq,
                               __bf16* __restrict__ wo) {
    const long long C0 = 786432;   // 6291456/8
    const long long C1 = 221184;   // 1769472/8
    const long long C2 = 73728;    // 589824/8
    long long i = (long long)blockIdx.x * blockDim.x + threadIdx.x;
    const long long stride = (long long)gridDim.x * blockDim.x;
    for (; i < C0 + C1 + C2; i += stride) {
        const float* src; __bf16* dst; long long j;
        if (i < C0)           { src = hs; dst = xh; j = i; }
        else if (i < C0 + C1) { src = w1; dst = wq; j = i - C0; }
        else                  { src = w2; dst = wo; j = i - C0 - C1; }
        f32x4 v0 = *(const f32x4*)(src + j * 8);
        f32x4 v1 = *(const f32x4*)(src + j * 8 + 4);
        bf16x8 o;
#pragma unroll
        for (int r = 0; r < 4; r++) { o[r] = (__bf16)v0[r]; o[4 + r] = (__bf16)v1[r]; }
        *(bf16x8*)(dst + j * 8) = o;
    }
}

// ---------------- NT bf16 MFMA GEMM: C = A(MxK) * B(NxK)^T + bias ----------------
// BM x 128 tile, BK=64, NBUF=2 (1 __syncthreads per K-step), XOR-swizzled LDS.
// MODE 0: two-phase bx ordering per XCD (A-slice + B-half = 3.25MB < 4MB L2);
//         vT blocks use the LDS-staged coalescing epilogue.
// MODE 1: plain bijective XCD swizzle; fp32 direct epilogue.
template <int MODE, int BM>
__global__ __launch_bounds__(BM * 4) void gemm_nt(
    const __bf16* __restrict__ A, const __bf16* __restrict__ Bm,
    const float* __restrict__ bias,
    __bf16* __restrict__ qb, __bf16* __restrict__ kb, __bf16* __restrict__ vT,
    float* __restrict__ outf, int M, int N, int K, int NXB)
{
    constexpr int THREADS = BM * 4;
    constexpr int ASZ = BM * 64 * 2;          // bytes per A buffer
    constexpr int BSZ = 128 * 64 * 2;         // bytes per B buffer
    constexpr int BUNITS = 1024 / THREADS;    // B stage units per thread
    constexpr int SMEMSZ = (MODE == 0) ? 66560 : (2 * ASZ + 2 * BSZ);
    __shared__ __align__(16) char SMEM[SMEMSZ];

    const int t = threadIdx.x;
    const int lane = t & 63;
    const int w = t >> 6;
    const int wr = w >> 2, wc = w & 3;        // wave tile 64x32
    const int fr = lane & 15, g4 = lane >> 4;

    const int cpx = gridDim.x >> 3;
    const int orig = blockIdx.x;
    int bx, by;
    if constexpr (MODE == 0) {
        const int xcd = orig & 7, idx = orig >> 3;
        const int halfSz = cpx >> 1;
        const int half = idx / halfSz, rem = idx - half * halfSz;
        const int halfN = NXB >> 1;
        by = xcd * (cpx / NXB) + rem / halfN;
        bx = half * halfN + rem % halfN;
    } else {
        const int swz = (orig & 7) * cpx + (orig >> 3);
        bx = swz % NXB; by = swz / NXB;
    }
    const int m0 = by * BM, n0 = bx * 128;

    f32x4 acc[4][2];
    const f32x4 z4 = {0.f, 0.f, 0.f, 0.f};
#pragma unroll
    for (int i = 0; i < 4; i++)
#pragma unroll
        for (int j = 0; j < 2; j++) acc[i][j] = z4;

    const int kSteps = K >> 6;

    auto As_ = [&](int b) { return (__bf16*)(SMEM + b * ASZ); };
    auto Bs_ = [&](int b) { return (__bf16*)(SMEM + 2 * ASZ + b * BSZ); };

    auto stage = [&](int tk, int b) {
#pragma unroll
        for (int u = 0; u < 2; u++) {
            const int c = u * THREADS + t;
            const int row = c >> 3;
            const int cb = ((c & 7) ^ (row & 7)) * 8;
            gload_lds16(A + (size_t)(m0 + row) * K + tk * 64 + cb, As_(b) + c * 8);
        }
#pragma unroll
        for (int u = 0; u < BUNITS; u++) {
            const int c = u * THREADS + t;
            const int row = c >> 3;
            const int cb = ((c & 7) ^ (row & 7)) * 8;
            gload_lds16(Bm + (size_t)(n0 + row) * K + tk * 64 + cb, Bs_(b) + c * 8);
        }
    };

    auto compute = [&](int cur) {
#pragma unroll
        for (int h = 0; h < 2; h++) {
            bf16x8 af[4], bfr[2];
#pragma unroll
            for (int i = 0; i < 4; i++) {
                const int r = wr * 64 + i * 16 + fr;
                af[i] = *(const bf16x8*)&As_(cur)[r * 64 + (((h * 4 + g4) ^ (r & 7)) * 8)];
            }
#pragma unroll
            for (int j = 0; j < 2; j++) {
                const int r = wc * 32 + j * 16 + fr;
                bfr[j] = *(const bf16x8*)&Bs_(cur)[r * 64 + (((h * 4 + g4) ^ (r & 7)) * 8)];
            }
            __builtin_amdgcn_s_setprio(1);
#pragma unroll
            for (int i = 0; i < 4; i++)
#pragma unroll
                for (int j = 0; j < 2; j++)
                    acc[i][j] = __builtin_amdgcn_mfma_f32_16x16x32_bf16(af[i], bfr[j], acc[i][j], 0, 0, 0);
            __builtin_amdgcn_s_setprio(0);
        }
    };

    stage(0, 0);
    __syncthreads();
    int cur = 0;
    for (int ks = 0; ks < kSteps; ks++) {
        if (ks < kSteps - 1) stage(ks + 1, cur ^ 1);
        compute(cur);
        __syncthreads();
        cur ^= 1;
    }

    if constexpr (MODE == 1) {
#pragma unroll
        for (int j = 0; j < 2; j++) {
            const int gc = n0 + wc * 32 + j * 16 + fr;
            const float bv = bias[gc];
#pragma unroll
            for (int i = 0; i < 4; i++)
#pragma unroll
                for (int r = 0; r < 4; r++) {
                    const int gr = m0 + wr * 64 + i * 16 + g4 * 4 + r;
                    outf[(size_t)gr * N + gc] = acc[i][j][r] + bv;
                }
        }
    } else {
        const int which = (n0 >= 1536) ? 2 : (n0 >= 768 ? 1 : 0);
        if (which < 2) {
#pragma unroll
            for (int j = 0; j < 2; j++) {
                const int gc = n0 + wc * 32 + j * 16 + fr;
                const float bv = bias[gc];
                const int jj = gc - which * 768;
                const int head = jj >> 6, dim = jj & 63;
#pragma unroll
                for (int i = 0; i < 4; i++)
#pragma unroll
                    for (int r = 0; r < 4; r++) {
                        const int gr = m0 + wr * 64 + i * 16 + g4 * 4 + r;
                        const int s = gr >> 3, b = gr & 7;
                        const size_t n = (size_t)(b * NH + head);
                        const float val = acc[i][j][r] + bv;
                        if (which == 0) qb[(n * 1024 + s) * 64 + dim] = (__bf16)(val * QSCALE);
                        else            kb[(n * 1024 + s) * 64 + dim] = (__bf16)val;
                    }
            }
        } else {
            float* Cw = (float*)SMEM;
#pragma unroll
            for (int j = 0; j < 2; j++) {
                const int col = wc * 32 + j * 16 + fr;
                const float bv = bias[n0 + col];
#pragma unroll
                for (int i = 0; i < 4; i++)
#pragma unroll
                    for (int r = 0; r < 4; r++) {
                        const int l = wr * 64 + i * 16 + g4 * 4 + r;
                        Cw[l * 130 + col] = acc[i][j][r] + bv;
                    }
            }
            __syncthreads();
            const int hbase = (n0 - 1536) >> 6;
            const int s0 = m0 >> 3;
#pragma unroll
            for (int u = 0; u < 2; u++) {
                const int c = u * THREADS + t;
                const int b = c >> 7;
                const int hd = (c >> 6) & 1;
                const int dim = c & 63;
                const size_t n = (size_t)(b * NH + hbase + hd);
                __bf16* dst = vT + (n * 64 + dim) * 1024 + s0;
                bf16x8 o0, o1;
#pragma unroll
                for (int sl = 0; sl < 8; sl++)
                    o0[sl] = (__bf16)Cw[(sl * 8 + b) * 130 + hd * 64 + dim];
#pragma unroll
                for (int sl = 0; sl < 8; sl++)
                    o1[sl] = (__bf16)Cw[((sl + 8) * 8 + b) * 130 + hd * 64 + dim];
                *(bf16x8*)dst = o0;
                *(bf16x8*)(dst + 8) = o1;
            }
        }
    }
}

// ---------------- flash attention ----------------
// K source-row permutation at staging (m173 pattern: linear LDS, permuted
// global source): Kl row (tt*16+rho) holds global key
//   kappa = 32*(tt>>1) + 8*(rho>>2) + 4*(tt&1) + (rho&3)
// so lane (fr,g4)'s 16 QK^T scores ARE the PV B-fragments in register order
// (p[0..7] = ks0, p[8..15] = ks1) — P never touches LDS. Ones-column denom
// (Vl row 64) as before. LDS 36KB/block -> 3+ blocks/CU.
__global__ __launch_bounds__(512) void attn_kernel(
    const __bf16* __restrict__ qb, const __bf16* __restrict__ kb,
    const __bf16* __restrict__ vT, __bf16* __restrict__ ctx)
{
    __shared__ __bf16 Kl[2][64 * 64];
    __shared__ __bf16 Vl[2][80 * 64];   // rows 64..79: ones-row + zeros
    const int t = threadIdx.x, lane = t & 63, w = t >> 6;

    const int orig = blockIdx.x;
    const int swz = (orig & 7) * 96 + (orig >> 3);
    const int n = swz >> 3;
    const int q0 = (swz & 7) * 128;
    const int fr = lane & 15, g4 = lane >> 4;
    const int fx = fr & 7;

    const __bf16* qptr = qb + ((size_t)n * 1024 + q0 + w * 16 + fr) * 64 + g4 * 8;
    const bf16x8 qf0 = *(const bf16x8*)qptr;
    const bf16x8 qf1 = *(const bf16x8*)(qptr + 32);

    float mval = -1e30f;
    const f32x4 z4 = {0.f, 0.f, 0.f, 0.f};
    f32x4 o[5] = {z4, z4, z4, z4, z4};   // o[4] = denominator accumulator

    const int srow = t >> 3;                 // LDS row this thread stages
    const int scb  = (t & 7) ^ (srow & 7);   // pre-swizzled col-chunk
    // key-row permutation: global key for LDS row srow
    const int tt_s = srow >> 4, rho = srow & 15;
    const int krow = 32 * (tt_s >> 1) + 8 * (rho >> 2) + 4 * (tt_s & 1) + (rho & 3);
    const __bf16* kbase = kb + (size_t)n * 65536;
    const __bf16* vbase = vT + (size_t)n * 65536;

    // init ones/zero rows 64..79 of both V buffers (4 bf16 per thread)
    {
        const int b = t >> 8;
        const int rem = (t * 4) & 1023;
        const int row = 64 + (rem >> 6), col = rem & 63;
        bf16x4 v;
        const __bf16 f = (__bf16)((row == 64) ? 1.0f : 0.0f);
        v[0] = f; v[1] = f; v[2] = f; v[3] = f;
        *(bf16x4*)&Vl[b][row * 64 + col] = v;
    }

    gload_lds16(kbase + (size_t)krow * 64 + scb * 8,   &Kl[0][t * 8]);
    gload_lds16(vbase + (size_t)srow * 1024 + scb * 8, &Vl[0][t * 8]);
    __syncthreads();

    int cur = 0;
    for (int kc = 0; kc < 16; kc++) {
        if (kc < 15) {
            const int t0 = (kc + 1) * 64;
            gload_lds16(kbase + (size_t)(t0 + krow) * 64 + scb * 8,  &Kl[cur ^ 1][t * 8]);
            gload_lds16(vbase + (size_t)srow * 1024 + t0 + scb * 8,  &Vl[cur ^ 1][t * 8]);
        }

        // ---- QK^T (swapped): sc[tt][r] = score[key = kappa(tt,4g4+r)][q = fr] ----
        f32x4 sc[4];
        __builtin_amdgcn_s_setprio(1);
#pragma unroll
        for (int tt = 0; tt < 4; tt++) {
            const int row = (tt * 16 + fr) * 64;
            bf16x8 kf0 = *(const bf16x8*)&Kl[cur][row + ((g4 ^ fx) * 8)];
            bf16x8 kf1 = *(const bf16x8*)&Kl[cur][row + (((4 + g4) ^ fx) * 8)];
            f32x4 s = __builtin_amdgcn_mfma_f32_16x16x32_bf16(kf0, qf0, z4, 0, 0, 0);
            s = __builtin_amdgcn_mfma_f32_16x16x32_bf16(kf1, qf1, s, 0, 0, 0);
            sc[tt] = s;
        }
        __builtin_amdgcn_s_setprio(0);

        // p[i]: key = 32*(i>>3) + 8*g4 + (i&7), q = fr  (register-ordered!)
        float a[16];
#pragma unroll
        for (int tt = 0; tt < 4; tt++)
#pragma unroll
            for (int r = 0; r < 4; r++) a[tt * 4 + r] = sc[tt][r];

        // ---- max via max3-fusable triples ----
        const float t0m = fmaxf(fmaxf(a[0],  a[1]),  a[2]);
        const float t1m = fmaxf(fmaxf(a[3],  a[4]),  a[5]);
        const float t2m = fmaxf(fmaxf(a[6],  a[7]),  a[8]);
        const float t3m = fmaxf(fmaxf(a[9],  a[10]), a[11]);
        const float t4m = fmaxf(fmaxf(a[12], a[13]), a[14]);
        float pmax = fmaxf(fmaxf(fmaxf(t0m, t1m), t2m),
                           fmaxf(fmaxf(t3m, t4m), a[15]));
        pmax = fmaxf(pmax, __shfl_xor(pmax, 16));
        pmax = fmaxf(pmax, __shfl_xor(pmax, 32));

        if (pmax > mval + 8.0f) {      // defer-max (exp2 domain; o[4] rescales too)
            const float sf = __builtin_amdgcn_exp2f(mval - pmax);
#pragma unroll
            for (int dt = 0; dt < 5; dt++) o[dt] *= sf;
            mval = pmax;
        }

        // ---- exp + pack straight into PV B-fragments (no LDS round-trip) ----
        bf16x8 pa0, pa1;
#pragma unroll
        for (int i = 0; i < 8; i++)  pa0[i] = (__bf16)__builtin_amdgcn_exp2f(a[i] - mval);
#pragma unroll
        for (int i = 0; i < 8; i++)  pa1[i] = (__bf16)__builtin_amdgcn_exp2f(a[8 + i] - mval);

        // ---- PV (swapped): o[dt][r] -> d = 16dt+4g4+r, q = fr; dt=4 = denom ----
        __builtin_amdgcn_s_setprio(1);
#pragma unroll
        for (int ks = 0; ks < 2; ks++) {
            const bf16x8 pa = ks ? pa1 : pa0;
#pragma unroll
            for (int dt = 0; dt < 5; dt++) {
                bf16x8 vf = *(const bf16x8*)&Vl[cur][(dt * 16 + fr) * 64 + (((4 * ks + g4) ^ fx) * 8)];
                o[dt] = __builtin_amdgcn_mfma_f32_16x16x32_bf16(vf, pa, o[dt], 0, 0, 0);
            }
        }
        __builtin_amdgcn_s_setprio(0);

        if (kc < 15) __syncthreads();
        cur ^= 1;
    }

    // denominator: lanes g4==0 hold it in o[4][0] (row 64); others hold 0 -> xor-add
    float lsum = o[4][0];
    lsum += __shfl_xor(lsum, 16);
    lsum += __shfl_xor(lsum, 32);

    const int b = n / NH, head = n % NH;
    const float rl = 1.0f / lsum;
    const int srw = q0 + w * 16 + fr;
    __bf16* cbase = ctx + ((size_t)srw * 8 + b) * 768 + head * 64;
#pragma unroll
    for (int dt = 0; dt < 4; dt++) {
        bf16x4 ov;
#pragma unroll
        for (int r = 0; r < 4; r++) ov[r] = (__bf16)(o[dt][r] * rl);
        *(bf16x4*)&cbase[dt * 16 + g4 * 4] = ov;
    }
}

extern "C" void kernel_launch(void* const* d_in, const int* in_sizes, int n_in,
                              void* d_out, int out_size, void* d_ws, size_t ws_size,
                              hipStream_t stream) {
    const float* hs = (const float*)d_in[0];
    const float* w1 = (const float*)d_in[1];
    const float* b1 = (const float*)d_in[2];
    const float* w2 = (const float*)d_in[3];
    const float* b2 = (const float*)d_in[4];
    float* out = (float*)d_out;

    char* ws = (char*)d_ws;
    __bf16* qb  = (__bf16*)(ws);
    __bf16* kb  = (__bf16*)(ws + 12582912);
    __bf16* vT  = (__bf16*)(ws + 25165824);
    __bf16* Xh  = (__bf16*)(ws + 37748736);
    __bf16* Wq  = (__bf16*)(ws + 50331648);
    __bf16* Wo  = (__bf16*)(ws + 53870592);
    __bf16* Ctx = Xh;                            // Xh dead after gemm0 -> reuse

    convert_kernel<<<2048, 256, 0, stream>>>(hs, w1, w2, Xh, Wq, Wo);
    gemm_nt<0, 128><<<1152, 512, 0, stream>>>(Xh, Wq, b1, qb, kb, vT, nullptr, 8192, 2304, 768, 18);
    attn_kernel<<<768, 512, 0, stream>>>(qb, kb, vT, Ctx);
    gemm_nt<1, 64><<<768, 256, 0, stream>>>(Ctx, Wo, b2, nullptr, nullptr, nullptr, out, 8192, 768, 768, 6);
}